// Round 6
// baseline (114.077 us; speedup 1.0000x reference)
//
#include <hip/hip_runtime.h>

// SelfAttention fwd: qkv GEMM -> causal flash attention -> proj GEMM, bf16 MFMA.
// B=8 T=1024 C=768 H=12 HD=64.

typedef unsigned short u16;
typedef unsigned int u32;
typedef __bf16 bf16x8 __attribute__((ext_vector_type(8)));
typedef float  f32x4  __attribute__((ext_vector_type(4)));
typedef float  f32x16 __attribute__((ext_vector_type(16)));
typedef unsigned short u16x4 __attribute__((ext_vector_type(4)));
typedef unsigned short u16x8 __attribute__((ext_vector_type(8)));

#define DEV static __device__ __forceinline__

constexpr int B_ = 8, T_ = 1024, C_ = 768, H_ = 12, HD_ = 64;
constexpr int M1 = B_ * T_;   // 8192
constexpr int N1 = 3 * C_;    // 2304
constexpr int KD = C_;        // 768

DEV u16 f2bf(float f) {
    union { float f; unsigned u; } v; v.f = f;
    unsigned r = v.u + 0x7fffu + ((v.u >> 16) & 1u);   // RNE
    return (u16)(r >> 16);
}

DEV u16 bfbits(float f) {  // native cast -> v_cvt (compiler may pack)
    __bf16 h = (__bf16)f;
    union { __bf16 h; u16 u; } v; v.h = h;
    return v.u;
}

DEV void gload16(const void* g, void* l) {
    // async global->LDS, 16B/lane; LDS dest = wave-uniform base + lane*16
    __builtin_amdgcn_global_load_lds(
        (const __attribute__((address_space(1))) unsigned*)g,
        (__attribute__((address_space(3))) unsigned*)l, 16, 0, 0);
}

DEV float redmax16(f32x16 v) {
    float a0 = fmaxf(v[0], v[1]), a1 = fmaxf(v[2], v[3]);
    float a2 = fmaxf(v[4], v[5]), a3 = fmaxf(v[6], v[7]);
    float a4 = fmaxf(v[8], v[9]), a5 = fmaxf(v[10], v[11]);
    float a6 = fmaxf(v[12], v[13]), a7 = fmaxf(v[14], v[15]);
    float b0 = fmaxf(a0, a1), b1 = fmaxf(a2, a3);
    float b2 = fmaxf(a4, a5), b3 = fmaxf(a6, a7);
    return fmaxf(fmaxf(b0, b1), fmaxf(b2, b3));
}
DEV float redsum16(f32x16 v) {
    float a0 = v[0] + v[1], a1 = v[2] + v[3], a2 = v[4] + v[5], a3 = v[6] + v[7];
    float a4 = v[8] + v[9], a5 = v[10] + v[11], a6 = v[12] + v[13], a7 = v[14] + v[15];
    float b0 = a0 + a1, b1 = a2 + a3, b2 = a4 + a5, b3 = a6 + a7;
    return (b0 + b1) + (b2 + b3);
}

// ---------------- convert kernels ----------------

__global__ __launch_bounds__(256) void cvt_x_kern(const float* __restrict__ x,
                                                  u16* __restrict__ xb, int n8) {
    int i = blockIdx.x * 256 + threadIdx.x;
    if (i >= n8) return;
    const float4* xf = (const float4*)x;
    float4 a = xf[i * 2], b = xf[i * 2 + 1];
    u16x8 o;
    o[0] = f2bf(a.x); o[1] = f2bf(a.y); o[2] = f2bf(a.z); o[3] = f2bf(a.w);
    o[4] = f2bf(b.x); o[5] = f2bf(b.y); o[6] = f2bf(b.z); o[7] = f2bf(b.w);
    *(u16x8*)(xb + (size_t)i * 8) = o;
}

// Both weights: W [K][N] fp32 row-major -> Wt [N][K=768] bf16 row-major.
// blockIdx.x < 72: W_qkv (N=2304); else W_proj (N=768).
__global__ __launch_bounds__(256) void cvt_w_kern(const float* __restrict__ Wq,
                                                  const float* __restrict__ Wp,
                                                  u16* __restrict__ WqT,
                                                  u16* __restrict__ WpT) {
    __shared__ float tile[32][33];
    int bx = blockIdx.x;
    const float* W; u16* Wt; int N;
    if (bx < N1 / 32) { W = Wq; Wt = WqT; N = N1; }
    else { bx -= N1 / 32; W = Wp; Wt = WpT; N = C_; }
    int n0 = bx * 32, k0 = blockIdx.y * 32;
    int tx = threadIdx.x & 31, ty = threadIdx.x >> 5;  // 32 x 8
#pragma unroll
    for (int i = 0; i < 4; i++) {
        int k = ty * 4 + i;
        tile[k][tx] = W[(size_t)(k0 + k) * N + n0 + tx];
    }
    __syncthreads();
#pragma unroll
    for (int i = 0; i < 4; i++) {
        int n = ty * 4 + i;
        Wt[(size_t)(n0 + n) * KD + k0 + tx] = f2bf(tile[tx][n]);
    }
}

// ---------------- GEMM (A [M][K] bf16, Bt [N][K] bf16) ----------------
// 128x128 tile, BK=64, double-buffered 2-phase: STAGE(next) -> compute(cur) ->
// one __syncthreads per K-step (drains vmcnt+lgkm, swaps buffers).
// XCD-chunked bijective block swizzle (grid % 8 == 0).
// MODE 0: qkv epilogue (scatter q*0.125/k/vT).  MODE 1: fp32 out + bias.

template <int MODE>
__global__ __launch_bounds__(256, 2) void gemm_bt_kern(
    const u16* __restrict__ A, const u16* __restrict__ Bt,
    const float* __restrict__ bias, int nBN,
    u16* __restrict__ qw, u16* __restrict__ kw, u16* __restrict__ vw,
    float* __restrict__ out) {
    __shared__ u16 ldsA[2][128 * 64];
    __shared__ u16 ldsB[2][128 * 64];
    // bijective XCD swizzle: same-XCD blocks get a contiguous bid chunk
    const int cpx = gridDim.x >> 3;
    const int bid = (blockIdx.x & 7) * cpx + (blockIdx.x >> 3);
    const int bm = bid / nBN, bn = bid % nBN;
    const int m0 = bm * 128, n0 = bn * 128;
    const int t = threadIdx.x;
    const int lane = t & 63, w = t >> 6;
    const int wr = w >> 1, wc = w & 1;
    const int l15 = lane & 15, lhi = lane >> 4;
    // staging: thread t covers tile-row (t>>3)+s*32, 16B chunk (t&7)
    const int srow = t >> 3;
    const int scb = ((t & 7) << 4) ^ ((srow & 7) << 4);  // pre-swizzled source chunk
    const char* Ab = (const char*)(A + (size_t)(m0 + srow) * KD) + scb;
    const char* Bb = (const char*)(Bt + (size_t)(n0 + srow) * KD) + scb;

    auto stage = [&](int buf, int k0) {
        char* lA = (char*)ldsA[buf] + w * 1024;  // uniform wave base; HW adds lane*16
        char* lB = (char*)ldsB[buf] + w * 1024;
#pragma unroll
        for (int s = 0; s < 4; s++) {
            gload16(Ab + (size_t)k0 * 2 + (size_t)s * 32 * KD * 2, lA + s * 4096);
            gload16(Bb + (size_t)k0 * 2 + (size_t)s * 32 * KD * 2, lB + s * 4096);
        }
    };

    stage(0, 0);
    __syncthreads();

    f32x4 acc[4][4] = {};
    constexpr int NSTEP = KD / 64;  // 12
    for (int st = 0; st < NSTEP; ++st) {
        const int cur = st & 1;
        if (st + 1 < NSTEP) stage(cur ^ 1, (st + 1) * 64);  // prefetch next tile
        const char* baseA = (const char*)ldsA[cur];
        const char* baseB = (const char*)ldsB[cur];
#pragma unroll
        for (int kk = 0; kk < 2; kk++) {
            bf16x8 af[4], bfr[4];
#pragma unroll
            for (int i = 0; i < 4; i++) {
                int rowA = wr * 64 + i * 16 + l15;
                af[i] = *(const bf16x8*)(baseA + rowA * 128 +
                                         ((kk * 64 + lhi * 16) ^ ((rowA & 7) << 4)));
                int rowB = wc * 64 + i * 16 + l15;
                bfr[i] = *(const bf16x8*)(baseB + rowB * 128 +
                                          ((kk * 64 + lhi * 16) ^ ((rowB & 7) << 4)));
            }
#pragma unroll
            for (int fm = 0; fm < 4; fm++)
#pragma unroll
                for (int fn = 0; fn < 4; fn++)
                    acc[fm][fn] = __builtin_amdgcn_mfma_f32_16x16x32_bf16(
                        af[fm], bfr[fn], acc[fm][fn], 0, 0, 0);
        }
        __syncthreads();  // drains this step's prefetch; protects cur for reuse
    }

    if constexpr (MODE == 1) {
#pragma unroll
        for (int fm = 0; fm < 4; fm++) {
            const int mb = m0 + wr * 64 + fm * 16 + lhi * 4;
#pragma unroll
            for (int fn = 0; fn < 4; fn++) {
                const int n = n0 + wc * 64 + fn * 16 + l15;
                const float bv = bias[n];
#pragma unroll
                for (int r = 0; r < 4; r++)
                    out[(size_t)(mb + r) * C_ + n] = acc[fm][fn][r] + bv;
            }
        }
    } else {
#pragma unroll
        for (int fn = 0; fn < 4; fn++) {
            const int c0 = n0 + wc * 64 + fn * 16;
            const int h3 = c0 >> 6;                 // wave-uniform head index
            const int d = (c0 & 63) + l15;
            const float bv = bias[c0 + l15];
#pragma unroll
            for (int fm = 0; fm < 4; fm++) {
                const int mb = m0 + wr * 64 + fm * 16 + lhi * 4;
                const int b = mb >> 10, tq = mb & 1023;
                if (h3 < H_) {
                    u16* dst = qw + ((size_t)(b * H_ + h3) * T_ + tq) * HD_ + d;
#pragma unroll
                    for (int r = 0; r < 4; r++)
                        dst[r * HD_] = f2bf((acc[fm][fn][r] + bv) * 0.125f);
                } else if (h3 < 2 * H_) {
                    u16* dst = kw + ((size_t)(b * H_ + (h3 - H_)) * T_ + tq) * HD_ + d;
#pragma unroll
                    for (int r = 0; r < 4; r++)
                        dst[r * HD_] = f2bf(acc[fm][fn][r] + bv);
                } else {
                    u16x4 p;
#pragma unroll
                    for (int r = 0; r < 4; r++) p[r] = f2bf(acc[fm][fn][r] + bv);
                    *(u16x4*)(vw + ((size_t)(b * H_ + (h3 - 2 * H_)) * HD_ + d) * T_ + tq) = p;
                }
            }
        }
    }
}

// ---------------- causal flash attention (swapped 32x32 MFMA) ----------------
// 256 threads / 4 waves, QBLK=128 (32 q-rows per wave via 32x32x16), KVBLK=64.
// S^T = K.Q^T : each lane owns ONE q-row (col = lane&31) -> lane-local softmax,
// only 2 cross-lane shfls per tile. O^T = V^T.P^T, acc col = q matches softmax.
// Q hoisted to registers; P relayout via per-wave swizzled LDS buffer.
// q pre-scaled by 1/8.  k [bh][t][64], vT [bh][64][t], out ao [b*t][h*64+d] bf16.

__global__ __launch_bounds__(256, 3) void attn_fwd_kern(
    const u16* __restrict__ qg, const u16* __restrict__ kg,
    const u16* __restrict__ vg, u16* __restrict__ ao) {
    __shared__ u16 kld[2][64 * 64];   // K tile: rows kv, cols k (swizzled)
    __shared__ u16 vld[2][64 * 64];   // V^T tile: rows d, cols kv (swizzled)
    __shared__ u16 pld[4][32 * 64];   // per-wave P [q][kv] (swizzled)
    const int n = blockIdx.x;
    const int bh = (n & 7) + 8 * ((n >> 3) % 12);
    const int qt = 7 - n / 96;            // big-work blocks first
    const int t = threadIdx.x, lane = t & 63, w = t >> 6;
    const int q5 = lane & 31, h2 = lane >> 5;
    const int srow = t >> 3;              // 0..31
    const int scb = ((t & 7) << 4) ^ ((srow & 7) << 4);
    const char* kb = (const char*)(kg + (size_t)bh * T_ * HD_);
    const char* vb = (const char*)(vg + (size_t)bh * HD_ * T_);

    // Q -> registers (B-frags): lane covers q-row qt*128+w*32+q5, k chunks
    const int qrow_g = qt * 128 + w * 32 + q5;
    const u16* qrow = qg + (size_t)bh * T_ * HD_ + (size_t)qrow_g * HD_ + h2 * 8;
    bf16x8 qf[4];
#pragma unroll
    for (int kc = 0; kc < 4; kc++)
        qf[kc] = *(const bf16x8*)(qrow + kc * 16);

    // stage K/V tile 0
#pragma unroll
    for (int s = 0; s < 2; s++) {
        gload16(kb + (size_t)(srow + s * 32) * 128 + scb,
                (char*)kld[0] + w * 1024 + s * 4096);
        gload16(vb + (size_t)(srow + s * 32) * 2048 + scb,
                (char*)vld[0] + w * 1024 + s * 4096);
    }
    __syncthreads();

    f32x16 acc[2] = {};
    float mst = -1e30f, lst = 0.f;
    const int qmax = qt * 128 + w * 32 + 31;
    char* pw = (char*)pld[w];

    const int ntiles = 2 * qt + 2;
    for (int kvt = 0; kvt < ntiles; kvt++) {
        const int cur = kvt & 1;
        if (kvt + 1 < ntiles) {  // prefetch next K/V tile
#pragma unroll
            for (int s = 0; s < 2; s++) {
                gload16(kb + (size_t)((kvt + 1) * 64 + srow + s * 32) * 128 + scb,
                        (char*)kld[cur ^ 1] + w * 1024 + s * 4096);
                gload16(vb + (size_t)(srow + s * 32) * 2048 + (kvt + 1) * 128 + scb,
                        (char*)vld[cur ^ 1] + w * 1024 + s * 4096);
            }
        }
        if (kvt * 64 <= qmax) {  // tile has at least one visible column for this wave
            const char* kbase = (const char*)kld[cur];
            const char* vbase = (const char*)vld[cur];
            // S^T = K . Q^T   (rows kv, cols q)
            f32x16 s0 = {}, s1 = {};
            __builtin_amdgcn_s_setprio(1);
#pragma unroll
            for (int kc = 0; kc < 4; kc++) {
                const int r0 = q5, r1 = 32 + q5;
                bf16x8 kf0 = *(const bf16x8*)(kbase + r0 * 128 +
                                              ((kc * 32 + h2 * 16) ^ ((r0 & 7) << 4)));
                bf16x8 kf1 = *(const bf16x8*)(kbase + r1 * 128 +
                                              ((kc * 32 + h2 * 16) ^ ((r1 & 7) << 4)));
                s0 = __builtin_amdgcn_mfma_f32_32x32x16_bf16(kf0, qf[kc], s0, 0, 0, 0);
                s1 = __builtin_amdgcn_mfma_f32_32x32x16_bf16(kf1, qf[kc], s1, 0, 0, 0);
            }
            __builtin_amdgcn_s_setprio(0);
            // causal mask (S^T reg r -> kv = (r&3)+8*(r>>2)+4*h2)
            if (kvt * 64 + 63 > qt * 128 + w * 32) {
                const int qg_ = qrow_g, kvb0 = kvt * 64 + 4 * h2;
#pragma unroll
                for (int r = 0; r < 16; r++) {
                    const int kvo = (r & 3) + 8 * (r >> 2);
                    if (kvb0 + kvo > qg_) s0[r] = -1e30f;
                    if (kvb0 + 32 + kvo > qg_) s1[r] = -1e30f;
                }
            }
            // lane-local online softmax (lane owns q-row q5; h2 halves duplicate)
            float pmax = fmaxf(redmax16(s0), redmax16(s1));
            pmax = fmaxf(pmax, __shfl_xor(pmax, 32));
            const float mn = fmaxf(mst, pmax);
            const float corr = __expf(mst - mn);
            mst = mn;
#pragma unroll
            for (int r = 0; r < 16; r++) {
                s0[r] = __expf(s0[r] - mn);
                s1[r] = __expf(s1[r] - mn);
            }
            float rs = redsum16(s0) + redsum16(s1);
            rs += __shfl_xor(rs, 32);
            lst = lst * corr + rs;
#pragma unroll
            for (int r = 0; r < 16; r++) { acc[0][r] *= corr; acc[1][r] *= corr; }
            // P -> per-wave LDS [q][kv] (pairs; swizzled), intra-wave dep only
            const int swz = (q5 & 7) << 4;
#pragma unroll
            for (int a = 0; a < 8; a++) {
                const int kv0 = ((2 * a) & 3) + 8 * (a >> 1) + 4 * h2;
                u32 pk0 = (u32)bfbits(s0[2 * a]) | ((u32)bfbits(s0[2 * a + 1]) << 16);
                u32 pk1 = (u32)bfbits(s1[2 * a]) | ((u32)bfbits(s1[2 * a + 1]) << 16);
                *(u32*)(pw + q5 * 128 + ((kv0 * 2) ^ swz)) = pk0;
                *(u32*)(pw + q5 * 128 + (((kv0 + 32) * 2) ^ swz)) = pk1;
            }
            // O^T += V^T . P^T
            bf16x8 pf[4];
#pragma unroll
            for (int m = 0; m < 4; m++)
                pf[m] = *(const bf16x8*)(pw + q5 * 128 + ((m * 32 + h2 * 16) ^ swz));
            __builtin_amdgcn_s_setprio(1);
#pragma unroll
            for (int m = 0; m < 4; m++) {
#pragma unroll
                for (int db = 0; db < 2; db++) {
                    const int rd = db * 32 + q5;
                    bf16x8 vf = *(const bf16x8*)(vbase + rd * 128 +
                                                 ((m * 32 + h2 * 16) ^ ((rd & 7) << 4)));
                    acc[db] = __builtin_amdgcn_mfma_f32_32x32x16_bf16(vf, pf[m], acc[db], 0, 0, 0);
                }
            }
            __builtin_amdgcn_s_setprio(0);
        }
        __syncthreads();  // prefetched tile ready; all waves done with buf[cur]
    }

    // epilogue: acc[db][r] = O[q = qrow_g][d = db*32 + (r&3) + 8*(r>>2) + 4*h2]
    const int b = bh / H_, h = bh % H_;
    const float inv = 1.0f / lst;
    u16* orow = ao + (size_t)(b * T_ + qrow_g) * C_ + h * 64 + 4 * h2;
#pragma unroll
    for (int db = 0; db < 2; db++)
#pragma unroll
        for (int q2 = 0; q2 < 4; q2++) {
            u16x4 pk;
#pragma unroll
            for (int e = 0; e < 4; e++) pk[e] = bfbits(acc[db][q2 * 4 + e] * inv);
            *(u16x4*)(orow + db * 32 + q2 * 8) = pk;
        }
}

// ---------------- launch ----------------

extern "C" void kernel_launch(void* const* d_in, const int* in_sizes, int n_in,
                              void* d_out, int out_size, void* d_ws, size_t ws_size,
                              hipStream_t stream) {
    const float* x     = (const float*)d_in[0];
    // d_in[1] = mask (causal tril) -- structure hard-coded
    const float* Wqkv  = (const float*)d_in[2];
    const float* bqkv  = (const float*)d_in[3];
    const float* Wproj = (const float*)d_in[4];
    const float* bproj = (const float*)d_in[5];
    float* out = (float*)d_out;

    char* ws = (char*)d_ws;
    u16* xb     = (u16*)(ws);                 // 12,582,912 B
    u16* wqkvT  = (u16*)(ws + 12582912);      //  3,538,944 B
    u16* wprojT = (u16*)(ws + 16121856);      //  1,179,648 B
    u16* qw     = (u16*)(ws + 17301504);      // 12,582,912 B  [B,H,T,64] (pre-scaled)
    u16* kw     = (u16*)(ws + 29884416);      // 12,582,912 B  [B,H,T,64]
    u16* vw     = (u16*)(ws + 42467328);      // 12,582,912 B  [B,H,64,T] (transposed)
    u16* ao     = (u16*)(ws + 55050240);      // 12,582,912 B  [B*T, C]

    cvt_x_kern<<<(M1 * C_ / 8 + 255) / 256, 256, 0, stream>>>(x, xb, M1 * C_ / 8);
    cvt_w_kern<<<dim3(N1 / 32 + C_ / 32, KD / 32), 256, 0, stream>>>(
        Wqkv, Wproj, wqkvT, wprojT);

    gemm_bt_kern<0><<<(M1 / 128) * (N1 / 128), 256, 0, stream>>>(
        xb, wqkvT, bqkv, N1 / 128, qw, kw, vw, nullptr);

    attn_fwd_kern<<<B_ * H_ * (T_ / 128), 256, 0, stream>>>(qw, kw, vw, ao);

    gemm_bt_kern<1><<<(M1 / 128) * (C_ / 128), 256, 0, stream>>>(
        ao, wprojT, bproj, C_ / 128, nullptr, nullptr, nullptr, out);
}

// Round 7
// 107.760 us; speedup vs baseline: 1.0586x; 1.0586x over previous
//
#include <hip/hip_runtime.h>

// SelfAttention fwd: qkv GEMM -> causal flash attention -> proj GEMM, bf16 MFMA.
// B=8 T=1024 C=768 H=12 HD=64.

typedef unsigned short u16;
typedef unsigned int u32;
typedef __bf16 bf16x8 __attribute__((ext_vector_type(8)));
typedef float  f32x4  __attribute__((ext_vector_type(4)));
typedef float  f32x16 __attribute__((ext_vector_type(16)));
typedef unsigned short u16x4 __attribute__((ext_vector_type(4)));
typedef unsigned short u16x8 __attribute__((ext_vector_type(8)));

#define DEV static __device__ __forceinline__

constexpr int B_ = 8, T_ = 1024, C_ = 768, H_ = 12, HD_ = 64;
constexpr int M1 = B_ * T_;   // 8192
constexpr int N1 = 3 * C_;    // 2304
constexpr int KD = C_;        // 768

DEV u16 f2bf(float f) {
    union { float f; unsigned u; } v; v.f = f;
    unsigned r = v.u + 0x7fffu + ((v.u >> 16) & 1u);   // RNE
    return (u16)(r >> 16);
}

DEV u16 bfbits(float f) {  // native cast -> v_cvt (compiler may pack)
    __bf16 h = (__bf16)f;
    union { __bf16 h; u16 u; } v; v.h = h;
    return v.u;
}

DEV void gload16(const void* g, void* l) {
    // async global->LDS, 16B/lane; LDS dest = wave-uniform base + lane*16
    __builtin_amdgcn_global_load_lds(
        (const __attribute__((address_space(1))) unsigned*)g,
        (__attribute__((address_space(3))) unsigned*)l, 16, 0, 0);
}

DEV float redmax16(f32x16 v) {
    float a0 = fmaxf(v[0], v[1]), a1 = fmaxf(v[2], v[3]);
    float a2 = fmaxf(v[4], v[5]), a3 = fmaxf(v[6], v[7]);
    float a4 = fmaxf(v[8], v[9]), a5 = fmaxf(v[10], v[11]);
    float a6 = fmaxf(v[12], v[13]), a7 = fmaxf(v[14], v[15]);
    float b0 = fmaxf(a0, a1), b1 = fmaxf(a2, a3);
    float b2 = fmaxf(a4, a5), b3 = fmaxf(a6, a7);
    return fmaxf(fmaxf(b0, b1), fmaxf(b2, b3));
}
DEV float redsum16(f32x16 v) {
    float a0 = v[0] + v[1], a1 = v[2] + v[3], a2 = v[4] + v[5], a3 = v[6] + v[7];
    float a4 = v[8] + v[9], a5 = v[10] + v[11], a6 = v[12] + v[13], a7 = v[14] + v[15];
    float b0 = a0 + a1, b1 = a2 + a3, b2 = a4 + a5, b3 = a6 + a7;
    return (b0 + b1) + (b2 + b3);
}

// ---------------- convert kernels ----------------

__global__ __launch_bounds__(256) void cvt_x_kern(const float* __restrict__ x,
                                                  u16* __restrict__ xb, int n8) {
    int i = blockIdx.x * 256 + threadIdx.x;
    if (i >= n8) return;
    const float4* xf = (const float4*)x;
    float4 a = xf[i * 2], b = xf[i * 2 + 1];
    u16x8 o;
    o[0] = f2bf(a.x); o[1] = f2bf(a.y); o[2] = f2bf(a.z); o[3] = f2bf(a.w);
    o[4] = f2bf(b.x); o[5] = f2bf(b.y); o[6] = f2bf(b.z); o[7] = f2bf(b.w);
    *(u16x8*)(xb + (size_t)i * 8) = o;
}

// Both weights: W [K][N] fp32 row-major -> Wt [N][K=768] bf16 row-major.
// blockIdx.x < 72: W_qkv (N=2304); else W_proj (N=768).
__global__ __launch_bounds__(256) void cvt_w_kern(const float* __restrict__ Wq,
                                                  const float* __restrict__ Wp,
                                                  u16* __restrict__ WqT,
                                                  u16* __restrict__ WpT) {
    __shared__ float tile[32][33];
    int bx = blockIdx.x;
    const float* W; u16* Wt; int N;
    if (bx < N1 / 32) { W = Wq; Wt = WqT; N = N1; }
    else { bx -= N1 / 32; W = Wp; Wt = WpT; N = C_; }
    int n0 = bx * 32, k0 = blockIdx.y * 32;
    int tx = threadIdx.x & 31, ty = threadIdx.x >> 5;  // 32 x 8
#pragma unroll
    for (int i = 0; i < 4; i++) {
        int k = ty * 4 + i;
        tile[k][tx] = W[(size_t)(k0 + k) * N + n0 + tx];
    }
    __syncthreads();
#pragma unroll
    for (int i = 0; i < 4; i++) {
        int n = ty * 4 + i;
        Wt[(size_t)(n0 + n) * KD + k0 + tx] = f2bf(tile[tx][n]);
    }
}

// ---------------- GEMM (A [M][K] bf16, Bt [N][K] bf16) ----------------
// 128x128 tile, BK=64, SINGLE-buffer (32KB LDS -> up to 5 blocks/CU; dbuf at
// 64KB capped residency at 2 and regressed -- round-6 lesson).
// XCD-chunked bijective block swizzle (grid % 8 == 0) keeps B/A panels L2-local.
// MODE 0: qkv epilogue (scatter q*0.125/k/vT).  MODE 1: fp32 out + bias.

template <int MODE>
__global__ __launch_bounds__(256, 2) void gemm_bt_kern(
    const u16* __restrict__ A, const u16* __restrict__ Bt,
    const float* __restrict__ bias, int nBN,
    u16* __restrict__ qw, u16* __restrict__ kw, u16* __restrict__ vw,
    float* __restrict__ out) {
    __shared__ u16 ldsA[128 * 64];
    __shared__ u16 ldsB[128 * 64];
    // bijective XCD swizzle: same-XCD blocks get a contiguous bid chunk
    const int cpx = gridDim.x >> 3;
    const int bid = (blockIdx.x & 7) * cpx + (blockIdx.x >> 3);
    const int bm = bid / nBN, bn = bid % nBN;
    const int m0 = bm * 128, n0 = bn * 128;
    const int t = threadIdx.x;
    const int lane = t & 63, w = t >> 6;
    const int wr = w >> 1, wc = w & 1;
    const int l15 = lane & 15, lhi = lane >> 4;
    // staging: thread t covers tile-row (t>>3)+s*32, 16B chunk (t&7)
    const int srow = t >> 3;
    const int scb = ((t & 7) << 4) ^ ((srow & 7) << 4);  // pre-swizzled source chunk
    const char* Ab = (const char*)(A + (size_t)(m0 + srow) * KD) + scb;
    const char* Bb = (const char*)(Bt + (size_t)(n0 + srow) * KD) + scb;
    char* lA = (char*)ldsA + w * 1024;  // uniform wave base; HW adds lane*16
    char* lB = (char*)ldsB + w * 1024;

    f32x4 acc[4][4] = {};

    for (int k0 = 0; k0 < KD; k0 += 64) {
#pragma unroll
        for (int s = 0; s < 4; s++) {
            gload16(Ab + (size_t)k0 * 2 + (size_t)s * 32 * KD * 2, lA + s * 4096);
            gload16(Bb + (size_t)k0 * 2 + (size_t)s * 32 * KD * 2, lB + s * 4096);
        }
        __syncthreads();
#pragma unroll
        for (int kk = 0; kk < 2; kk++) {
            bf16x8 af[4], bfr[4];
#pragma unroll
            for (int i = 0; i < 4; i++) {
                int rowA = wr * 64 + i * 16 + l15;
                af[i] = *(const bf16x8*)((const char*)ldsA + rowA * 128 +
                                         ((kk * 64 + lhi * 16) ^ ((rowA & 7) << 4)));
                int rowB = wc * 64 + i * 16 + l15;
                bfr[i] = *(const bf16x8*)((const char*)ldsB + rowB * 128 +
                                          ((kk * 64 + lhi * 16) ^ ((rowB & 7) << 4)));
            }
#pragma unroll
            for (int fm = 0; fm < 4; fm++)
#pragma unroll
                for (int fn = 0; fn < 4; fn++)
                    acc[fm][fn] = __builtin_amdgcn_mfma_f32_16x16x32_bf16(
                        af[fm], bfr[fn], acc[fm][fn], 0, 0, 0);
        }
        __syncthreads();
    }

    if constexpr (MODE == 1) {
#pragma unroll
        for (int fm = 0; fm < 4; fm++) {
            const int mb = m0 + wr * 64 + fm * 16 + lhi * 4;
#pragma unroll
            for (int fn = 0; fn < 4; fn++) {
                const int n = n0 + wc * 64 + fn * 16 + l15;
                const float bv = bias[n];
#pragma unroll
                for (int r = 0; r < 4; r++)
                    out[(size_t)(mb + r) * C_ + n] = acc[fm][fn][r] + bv;
            }
        }
    } else {
#pragma unroll
        for (int fn = 0; fn < 4; fn++) {
            const int c0 = n0 + wc * 64 + fn * 16;
            const int h3 = c0 >> 6;                 // wave-uniform head index
            const int d = (c0 & 63) + l15;
            const float bv = bias[c0 + l15];
#pragma unroll
            for (int fm = 0; fm < 4; fm++) {
                const int mb = m0 + wr * 64 + fm * 16 + lhi * 4;
                const int b = mb >> 10, tq = mb & 1023;
                if (h3 < H_) {
                    u16* dst = qw + ((size_t)(b * H_ + h3) * T_ + tq) * HD_ + d;
#pragma unroll
                    for (int r = 0; r < 4; r++)
                        dst[r * HD_] = f2bf((acc[fm][fn][r] + bv) * 0.125f);
                } else if (h3 < 2 * H_) {
                    u16* dst = kw + ((size_t)(b * H_ + (h3 - H_)) * T_ + tq) * HD_ + d;
#pragma unroll
                    for (int r = 0; r < 4; r++)
                        dst[r * HD_] = f2bf(acc[fm][fn][r] + bv);
                } else {
                    u16x4 p;
#pragma unroll
                    for (int r = 0; r < 4; r++) p[r] = f2bf(acc[fm][fn][r] + bv);
                    *(u16x4*)(vw + ((size_t)(b * H_ + (h3 - 2 * H_)) * HD_ + d) * T_ + tq) = p;
                }
            }
        }
    }
}

// ---------------- causal flash attention (swapped 32x32 MFMA) ----------------
// 256 threads / 4 waves, QBLK=128 (32 q-rows per wave via 32x32x16), KVBLK=64.
// S^T = K.Q^T : each lane owns ONE q-row (col = lane&31) -> lane-local softmax,
// only 2 cross-lane shfls per tile. O^T = V^T.P^T, acc col = q matches softmax.
// Q hoisted to registers; P relayout via per-wave swizzled LDS buffer.
// q pre-scaled by 1/8.  k [bh][t][64], vT [bh][64][t], out ao [b*t][h*64+d] bf16.

__global__ __launch_bounds__(256, 3) void attn_fwd_kern(
    const u16* __restrict__ qg, const u16* __restrict__ kg,
    const u16* __restrict__ vg, u16* __restrict__ ao) {
    __shared__ u16 kld[2][64 * 64];   // K tile: rows kv, cols k (swizzled)
    __shared__ u16 vld[2][64 * 64];   // V^T tile: rows d, cols kv (swizzled)
    __shared__ u16 pld[4][32 * 64];   // per-wave P [q][kv] (swizzled)
    const int n = blockIdx.x;
    const int bh = (n & 7) + 8 * ((n >> 3) % 12);
    const int qt = 7 - n / 96;            // big-work blocks first
    const int t = threadIdx.x, lane = t & 63, w = t >> 6;
    const int q5 = lane & 31, h2 = lane >> 5;
    const int srow = t >> 3;              // 0..31
    const int scb = ((t & 7) << 4) ^ ((srow & 7) << 4);
    const char* kb = (const char*)(kg + (size_t)bh * T_ * HD_);
    const char* vb = (const char*)(vg + (size_t)bh * HD_ * T_);

    // Q -> registers (B-frags): lane covers q-row qt*128+w*32+q5, k chunks
    const int qrow_g = qt * 128 + w * 32 + q5;
    const u16* qrow = qg + (size_t)bh * T_ * HD_ + (size_t)qrow_g * HD_ + h2 * 8;
    bf16x8 qf[4];
#pragma unroll
    for (int kc = 0; kc < 4; kc++)
        qf[kc] = *(const bf16x8*)(qrow + kc * 16);

    // stage K/V tile 0
#pragma unroll
    for (int s = 0; s < 2; s++) {
        gload16(kb + (size_t)(srow + s * 32) * 128 + scb,
                (char*)kld[0] + w * 1024 + s * 4096);
        gload16(vb + (size_t)(srow + s * 32) * 2048 + scb,
                (char*)vld[0] + w * 1024 + s * 4096);
    }
    __syncthreads();

    f32x16 acc[2] = {};
    float mst = -1e30f, lst = 0.f;
    const int qmax = qt * 128 + w * 32 + 31;
    char* pw = (char*)pld[w];

    const int ntiles = 2 * qt + 2;
    for (int kvt = 0; kvt < ntiles; kvt++) {
        const int cur = kvt & 1;
        if (kvt + 1 < ntiles) {  // prefetch next K/V tile
#pragma unroll
            for (int s = 0; s < 2; s++) {
                gload16(kb + (size_t)((kvt + 1) * 64 + srow + s * 32) * 128 + scb,
                        (char*)kld[cur ^ 1] + w * 1024 + s * 4096);
                gload16(vb + (size_t)(srow + s * 32) * 2048 + (kvt + 1) * 128 + scb,
                        (char*)vld[cur ^ 1] + w * 1024 + s * 4096);
            }
        }
        if (kvt * 64 <= qmax) {  // tile has at least one visible column for this wave
            const char* kbase = (const char*)kld[cur];
            const char* vbase = (const char*)vld[cur];
            // S^T = K . Q^T   (rows kv, cols q)
            f32x16 s0 = {}, s1 = {};
            __builtin_amdgcn_s_setprio(1);
#pragma unroll
            for (int kc = 0; kc < 4; kc++) {
                const int r0 = q5, r1 = 32 + q5;
                bf16x8 kf0 = *(const bf16x8*)(kbase + r0 * 128 +
                                              ((kc * 32 + h2 * 16) ^ ((r0 & 7) << 4)));
                bf16x8 kf1 = *(const bf16x8*)(kbase + r1 * 128 +
                                              ((kc * 32 + h2 * 16) ^ ((r1 & 7) << 4)));
                s0 = __builtin_amdgcn_mfma_f32_32x32x16_bf16(kf0, qf[kc], s0, 0, 0, 0);
                s1 = __builtin_amdgcn_mfma_f32_32x32x16_bf16(kf1, qf[kc], s1, 0, 0, 0);
            }
            __builtin_amdgcn_s_setprio(0);
            // causal mask (S^T reg r -> kv = (r&3)+8*(r>>2)+4*h2)
            if (kvt * 64 + 63 > qt * 128 + w * 32) {
                const int qg_ = qrow_g, kvb0 = kvt * 64 + 4 * h2;
#pragma unroll
                for (int r = 0; r < 16; r++) {
                    const int kvo = (r & 3) + 8 * (r >> 2);
                    if (kvb0 + kvo > qg_) s0[r] = -1e30f;
                    if (kvb0 + 32 + kvo > qg_) s1[r] = -1e30f;
                }
            }
            // lane-local online softmax (lane owns q-row q5; h2 halves duplicate)
            float pmax = fmaxf(redmax16(s0), redmax16(s1));
            pmax = fmaxf(pmax, __shfl_xor(pmax, 32));
            const float mn = fmaxf(mst, pmax);
            const float corr = __expf(mst - mn);
            mst = mn;
#pragma unroll
            for (int r = 0; r < 16; r++) {
                s0[r] = __expf(s0[r] - mn);
                s1[r] = __expf(s1[r] - mn);
            }
            float rs = redsum16(s0) + redsum16(s1);
            rs += __shfl_xor(rs, 32);
            lst = lst * corr + rs;
#pragma unroll
            for (int r = 0; r < 16; r++) { acc[0][r] *= corr; acc[1][r] *= corr; }
            // P -> per-wave LDS [q][kv] (pairs; swizzled), intra-wave dep only
            const int swz = (q5 & 7) << 4;
#pragma unroll
            for (int a = 0; a < 8; a++) {
                const int kv0 = ((2 * a) & 3) + 8 * (a >> 1) + 4 * h2;
                u32 pk0 = (u32)bfbits(s0[2 * a]) | ((u32)bfbits(s0[2 * a + 1]) << 16);
                u32 pk1 = (u32)bfbits(s1[2 * a]) | ((u32)bfbits(s1[2 * a + 1]) << 16);
                *(u32*)(pw + q5 * 128 + ((kv0 * 2) ^ swz)) = pk0;
                *(u32*)(pw + q5 * 128 + (((kv0 + 32) * 2) ^ swz)) = pk1;
            }
            // O^T += V^T . P^T
            bf16x8 pf[4];
#pragma unroll
            for (int m = 0; m < 4; m++)
                pf[m] = *(const bf16x8*)(pw + q5 * 128 + ((m * 32 + h2 * 16) ^ swz));
            __builtin_amdgcn_s_setprio(1);
#pragma unroll
            for (int m = 0; m < 4; m++) {
#pragma unroll
                for (int db = 0; db < 2; db++) {
                    const int rd = db * 32 + q5;
                    bf16x8 vf = *(const bf16x8*)(vbase + rd * 128 +
                                                 ((m * 32 + h2 * 16) ^ ((rd & 7) << 4)));
                    acc[db] = __builtin_amdgcn_mfma_f32_32x32x16_bf16(vf, pf[m], acc[db], 0, 0, 0);
                }
            }
            __builtin_amdgcn_s_setprio(0);
        }
        __syncthreads();  // prefetched tile ready; all waves done with buf[cur]
    }

    // epilogue: acc[db][r] = O[q = qrow_g][d = db*32 + (r&3) + 8*(r>>2) + 4*h2]
    const int b = bh / H_, h = bh % H_;
    const float inv = 1.0f / lst;
    u16* orow = ao + (size_t)(b * T_ + qrow_g) * C_ + h * 64 + 4 * h2;
#pragma unroll
    for (int db = 0; db < 2; db++)
#pragma unroll
        for (int q2 = 0; q2 < 4; q2++) {
            u16x4 pk;
#pragma unroll
            for (int e = 0; e < 4; e++) pk[e] = bfbits(acc[db][q2 * 4 + e] * inv);
            *(u16x4*)(orow + db * 32 + q2 * 8) = pk;
        }
}

// ---------------- launch ----------------

extern "C" void kernel_launch(void* const* d_in, const int* in_sizes, int n_in,
                              void* d_out, int out_size, void* d_ws, size_t ws_size,
                              hipStream_t stream) {
    const float* x     = (const float*)d_in[0];
    // d_in[1] = mask (causal tril) -- structure hard-coded
    const float* Wqkv  = (const float*)d_in[2];
    const float* bqkv  = (const float*)d_in[3];
    const float* Wproj = (const float*)d_in[4];
    const float* bproj = (const float*)d_in[5];
    float* out = (float*)d_out;

    char* ws = (char*)d_ws;
    u16* xb     = (u16*)(ws);                 // 12,582,912 B
    u16* wqkvT  = (u16*)(ws + 12582912);      //  3,538,944 B
    u16* wprojT = (u16*)(ws + 16121856);      //  1,179,648 B
    u16* qw     = (u16*)(ws + 17301504);      // 12,582,912 B  [B,H,T,64] (pre-scaled)
    u16* kw     = (u16*)(ws + 29884416);      // 12,582,912 B  [B,H,T,64]
    u16* vw     = (u16*)(ws + 42467328);      // 12,582,912 B  [B,H,64,T] (transposed)
    u16* ao     = (u16*)(ws + 55050240);      // 12,582,912 B  [B*T, C]

    cvt_x_kern<<<(M1 * C_ / 8 + 255) / 256, 256, 0, stream>>>(x, xb, M1 * C_ / 8);
    cvt_w_kern<<<dim3(N1 / 32 + C_ / 32, KD / 32), 256, 0, stream>>>(
        Wqkv, Wproj, wqkvT, wprojT);

    gemm_bt_kern<0><<<(M1 / 128) * (N1 / 128), 256, 0, stream>>>(
        xb, wqkvT, bqkv, N1 / 128, qw, kw, vw, nullptr);

    attn_fwd_kern<<<B_ * H_ * (T_ / 128), 256, 0, stream>>>(qw, kw, vw, ao);

    gemm_bt_kern<1><<<(M1 / 128) * (C_ / 128), 256, 0, stream>>>(
        ao, wprojT, bproj, C_ / 128, nullptr, nullptr, nullptr, out);
}

// Round 8
// 103.608 us; speedup vs baseline: 1.1010x; 1.0401x over previous
//
#include <hip/hip_runtime.h>

// SelfAttention fwd: qkv GEMM -> causal flash attention -> proj GEMM, bf16 MFMA.
// B=8 T=1024 C=768 H=12 HD=64.

typedef unsigned short u16;
typedef unsigned int u32;
typedef __bf16 bf16x8 __attribute__((ext_vector_type(8)));
typedef float  f32x4  __attribute__((ext_vector_type(4)));
typedef float  f32x16 __attribute__((ext_vector_type(16)));
typedef unsigned short u16x4 __attribute__((ext_vector_type(4)));
typedef unsigned short u16x8 __attribute__((ext_vector_type(8)));

#define DEV static __device__ __forceinline__

constexpr int B_ = 8, T_ = 1024, C_ = 768, H_ = 12, HD_ = 64;
constexpr int M1 = B_ * T_;   // 8192
constexpr int N1 = 3 * C_;    // 2304
constexpr int KD = C_;        // 768

DEV u16 f2bf(float f) {
    union { float f; unsigned u; } v; v.f = f;
    unsigned r = v.u + 0x7fffu + ((v.u >> 16) & 1u);   // RNE
    return (u16)(r >> 16);
}

DEV u16 bfbits(float f) {  // native cast -> v_cvt (compiler may pack)
    __bf16 h = (__bf16)f;
    union { __bf16 h; u16 u; } v; v.h = h;
    return v.u;
}

DEV void gload16(const void* g, void* l) {
    // async global->LDS, 16B/lane; LDS dest = wave-uniform base + lane*16
    __builtin_amdgcn_global_load_lds(
        (const __attribute__((address_space(1))) unsigned*)g,
        (__attribute__((address_space(3))) unsigned*)l, 16, 0, 0);
}

DEV float redmax16(f32x16 v) {
    float a0 = fmaxf(v[0], v[1]), a1 = fmaxf(v[2], v[3]);
    float a2 = fmaxf(v[4], v[5]), a3 = fmaxf(v[6], v[7]);
    float a4 = fmaxf(v[8], v[9]), a5 = fmaxf(v[10], v[11]);
    float a6 = fmaxf(v[12], v[13]), a7 = fmaxf(v[14], v[15]);
    float b0 = fmaxf(a0, a1), b1 = fmaxf(a2, a3);
    float b2 = fmaxf(a4, a5), b3 = fmaxf(a6, a7);
    return fmaxf(fmaxf(b0, b1), fmaxf(b2, b3));
}
DEV float redsum16(f32x16 v) {
    float a0 = v[0] + v[1], a1 = v[2] + v[3], a2 = v[4] + v[5], a3 = v[6] + v[7];
    float a4 = v[8] + v[9], a5 = v[10] + v[11], a6 = v[12] + v[13], a7 = v[14] + v[15];
    float b0 = a0 + a1, b1 = a2 + a3, b2 = a4 + a5, b3 = a6 + a7;
    return (b0 + b1) + (b2 + b3);
}

// ---------------- convert kernels ----------------

__global__ __launch_bounds__(256) void cvt_x_kern(const float* __restrict__ x,
                                                  u16* __restrict__ xb, int n8) {
    int i = blockIdx.x * 256 + threadIdx.x;
    if (i >= n8) return;
    const float4* xf = (const float4*)x;
    float4 a = xf[i * 2], b = xf[i * 2 + 1];
    u16x8 o;
    o[0] = f2bf(a.x); o[1] = f2bf(a.y); o[2] = f2bf(a.z); o[3] = f2bf(a.w);
    o[4] = f2bf(b.x); o[5] = f2bf(b.y); o[6] = f2bf(b.z); o[7] = f2bf(b.w);
    *(u16x8*)(xb + (size_t)i * 8) = o;
}

// Both weights: W [K][N] fp32 row-major -> Wt [N][K=768] bf16 row-major.
// blockIdx.x < 72: W_qkv (N=2304); else W_proj (N=768).
__global__ __launch_bounds__(256) void cvt_w_kern(const float* __restrict__ Wq,
                                                  const float* __restrict__ Wp,
                                                  u16* __restrict__ WqT,
                                                  u16* __restrict__ WpT) {
    __shared__ float tile[32][33];
    int bx = blockIdx.x;
    const float* W; u16* Wt; int N;
    if (bx < N1 / 32) { W = Wq; Wt = WqT; N = N1; }
    else { bx -= N1 / 32; W = Wp; Wt = WpT; N = C_; }
    int n0 = bx * 32, k0 = blockIdx.y * 32;
    int tx = threadIdx.x & 31, ty = threadIdx.x >> 5;  // 32 x 8
#pragma unroll
    for (int i = 0; i < 4; i++) {
        int k = ty * 4 + i;
        tile[k][tx] = W[(size_t)(k0 + k) * N + n0 + tx];
    }
    __syncthreads();
#pragma unroll
    for (int i = 0; i < 4; i++) {
        int n = ty * 4 + i;
        Wt[(size_t)(n0 + n) * KD + k0 + tx] = f2bf(tile[tx][n]);
    }
}

// ---------------- GEMM (A [M][K] bf16, Bt [N][K] bf16) ----------------
// 128x128 tile, BK=64, single-buffer 32KB LDS (round-6 lesson: dbuf cut
// occupancy and regressed). XCD-chunked bijective block swizzle.
// MODE 0: qkv epilogue via LDS re-tile -> fully coalesced u16x8 stores
//         (q/k row-major swizzled tile; v transposed tile). Round-7 lesson:
//         direct scatter stores gave 55.7MB HBM writes vs 37.7 ideal.
// MODE 1: fp32 out + bias (64B-per-lane-group rows, lines fully covered).

template <int MODE>
__global__ __launch_bounds__(256, 2) void gemm_bt_kern(
    const u16* __restrict__ A, const u16* __restrict__ Bt,
    const float* __restrict__ bias, int nBN,
    u16* __restrict__ qw, u16* __restrict__ kw, u16* __restrict__ vw,
    float* __restrict__ out) {
    __shared__ u16 lds[16384];          // 32KB: A-tile 16KB + B-tile 16KB
    char* LA = (char*)lds;
    char* LB = (char*)lds + 16384;
    // bijective XCD swizzle: same-XCD blocks get a contiguous bid chunk
    const int cpx = gridDim.x >> 3;
    const int bid = (blockIdx.x & 7) * cpx + (blockIdx.x >> 3);
    const int bm = bid / nBN, bn = bid % nBN;
    const int m0 = bm * 128, n0 = bn * 128;
    const int t = threadIdx.x;
    const int lane = t & 63, w = t >> 6;
    const int wr = w >> 1, wc = w & 1;
    const int l15 = lane & 15, lhi = lane >> 4;
    // staging: thread t covers tile-row (t>>3)+s*32, 16B chunk (t&7)
    const int srow = t >> 3;
    const int scb = ((t & 7) << 4) ^ ((srow & 7) << 4);  // pre-swizzled source chunk
    const char* Ab = (const char*)(A + (size_t)(m0 + srow) * KD) + scb;
    const char* Bb = (const char*)(Bt + (size_t)(n0 + srow) * KD) + scb;

    f32x4 acc[4][4] = {};

    for (int k0 = 0; k0 < KD; k0 += 64) {
#pragma unroll
        for (int s = 0; s < 4; s++) {
            gload16(Ab + (size_t)k0 * 2 + (size_t)s * 32 * KD * 2, LA + w * 1024 + s * 4096);
            gload16(Bb + (size_t)k0 * 2 + (size_t)s * 32 * KD * 2, LB + w * 1024 + s * 4096);
        }
        __syncthreads();
#pragma unroll
        for (int kk = 0; kk < 2; kk++) {
            bf16x8 af[4], bfr[4];
#pragma unroll
            for (int i = 0; i < 4; i++) {
                int rowA = wr * 64 + i * 16 + l15;
                af[i] = *(const bf16x8*)(LA + rowA * 128 +
                                         ((kk * 64 + lhi * 16) ^ ((rowA & 7) << 4)));
                int rowB = wc * 64 + i * 16 + l15;
                bfr[i] = *(const bf16x8*)(LB + rowB * 128 +
                                          ((kk * 64 + lhi * 16) ^ ((rowB & 7) << 4)));
            }
#pragma unroll
            for (int fm = 0; fm < 4; fm++)
#pragma unroll
                for (int fn = 0; fn < 4; fn++)
                    acc[fm][fn] = __builtin_amdgcn_mfma_f32_16x16x32_bf16(
                        af[fm], bfr[fn], acc[fm][fn], 0, 0, 0);
        }
        __syncthreads();
    }

    if constexpr (MODE == 1) {
#pragma unroll
        for (int fm = 0; fm < 4; fm++) {
            const int mb = m0 + wr * 64 + fm * 16 + lhi * 4;
#pragma unroll
            for (int fn = 0; fn < 4; fn++) {
                const int n = n0 + wc * 64 + fn * 16 + l15;
                const float bv = bias[n];
#pragma unroll
                for (int r = 0; r < 4; r++)
                    out[(size_t)(mb + r) * C_ + n] = acc[fm][fn][r] + bv;
            }
        }
    } else {
        // epilogue via LDS re-tile (K-loop ended with syncthreads -> LDS free).
        // Block's n-range is uniformly one of q/k/v: bn 0-5 q, 6-11 k, 12-17 v.
        char* TT = (char*)lds;          // 128x128 bf16 = 32KB
        const int typ = bn / 6;         // 0=q, 1=k, 2=v
        const int h0 = (bn % 6) * 2;    // first head covered by this tile
        if (typ < 2) {
            const float sc = (typ == 0) ? 0.125f : 1.0f;
            // row-major T[row=m][col=n], byte = row*256 + ((col*2)^((row&7)<<5))
#pragma unroll
            for (int fn = 0; fn < 4; fn++) {
                const int col = wc * 64 + fn * 16 + l15;
                const float bv = bias[n0 + col];
#pragma unroll
                for (int fm = 0; fm < 4; fm++) {
                    const int row0 = wr * 64 + fm * 16 + lhi * 4;
#pragma unroll
                    for (int r = 0; r < 4; r++) {
                        const int row = row0 + r;
                        *(u16*)(TT + row * 256 + ((col * 2) ^ ((row & 7) << 5))) =
                            bfbits((acc[fm][fn][r] + bv) * sc);
                    }
                }
            }
            __syncthreads();
            u16* dst = (typ == 0) ? qw : kw;
#pragma unroll
            for (int i = 0; i < 8; i++) {
                const int wk = t + 256 * i;          // 0..2047 16B chunks
                const int m = wk >> 4, c = wk & 15;  // 16 chunks per row
                u16x8 v8 = *(u16x8*)(TT + m * 256 + ((c * 16) ^ ((m & 7) << 5)));
                const int mb = m0 + m, b = mb >> 10, tq = mb & 1023;
                const int h = h0 + (c >> 3), d0 = (c & 7) * 8;
                *(u16x8*)(dst + (((size_t)(b * H_ + h) * T_ + tq) << 6) + d0) = v8;
            }
        } else {
            // transposed T'[col=n][row=m], packed u16x4 (4 consecutive m / lane)
            // byte = col*256 + ((row*2)^((col&7)<<4))
#pragma unroll
            for (int fn = 0; fn < 4; fn++) {
                const int col = wc * 64 + fn * 16 + l15;
                const float bv = bias[n0 + col];
                const int cx = (col & 7) << 4;
#pragma unroll
                for (int fm = 0; fm < 4; fm++) {
                    const int row0 = wr * 64 + fm * 16 + lhi * 4;
                    u16x4 pk;
#pragma unroll
                    for (int r = 0; r < 4; r++) pk[r] = bfbits(acc[fm][fn][r] + bv);
                    *(u16x4*)(TT + col * 256 + ((row0 * 2) ^ cx)) = pk;
                }
            }
            __syncthreads();
#pragma unroll
            for (int i = 0; i < 8; i++) {
                const int wk = t + 256 * i;
                const int col = wk >> 4, ch = wk & 15;
                u16x8 v8 = *(u16x8*)(TT + col * 256 + ((ch * 16) ^ ((col & 7) << 4)));
                const int b = m0 >> 10, tq0 = (m0 & 1023) + ch * 8;
                const int h = h0 + (col >> 6), d = col & 63;
                *(u16x8*)(vw + (((size_t)(b * H_ + h) * HD_ + d) << 10) + tq0) = v8;
            }
        }
    }
}

// ---------------- causal flash attention (swapped 32x32 MFMA) ----------------
// 256 threads / 4 waves, QBLK=128 (32 q-rows per wave via 32x32x16), KVBLK=64.
// S^T = K.Q^T : each lane owns ONE q-row (col = lane&31) -> lane-local softmax,
// only 2 cross-lane shfls per tile. O^T = V^T.P^T, acc col = q matches softmax.
// Q hoisted to registers; P relayout via per-wave swizzled LDS buffer.
// q pre-scaled by 1/8.  k [bh][t][64], vT [bh][64][t], out ao [b*t][h*64+d] bf16.

__global__ __launch_bounds__(256, 3) void attn_fwd_kern(
    const u16* __restrict__ qg, const u16* __restrict__ kg,
    const u16* __restrict__ vg, u16* __restrict__ ao) {
    __shared__ u16 kld[2][64 * 64];   // K tile: rows kv, cols k (swizzled)
    __shared__ u16 vld[2][64 * 64];   // V^T tile: rows d, cols kv (swizzled)
    __shared__ u16 pld[4][32 * 64];   // per-wave P [q][kv] (swizzled)
    const int n = blockIdx.x;
    const int bh = (n & 7) + 8 * ((n >> 3) % 12);
    const int qt = 7 - n / 96;            // big-work blocks first
    const int t = threadIdx.x, lane = t & 63, w = t >> 6;
    const int q5 = lane & 31, h2 = lane >> 5;
    const int srow = t >> 3;              // 0..31
    const int scb = ((t & 7) << 4) ^ ((srow & 7) << 4);
    const char* kb = (const char*)(kg + (size_t)bh * T_ * HD_);
    const char* vb = (const char*)(vg + (size_t)bh * HD_ * T_);

    // Q -> registers (B-frags): lane covers q-row qt*128+w*32+q5, k chunks
    const int qrow_g = qt * 128 + w * 32 + q5;
    const u16* qrow = qg + (size_t)bh * T_ * HD_ + (size_t)qrow_g * HD_ + h2 * 8;
    bf16x8 qf[4];
#pragma unroll
    for (int kc = 0; kc < 4; kc++)
        qf[kc] = *(const bf16x8*)(qrow + kc * 16);

    // stage K/V tile 0
#pragma unroll
    for (int s = 0; s < 2; s++) {
        gload16(kb + (size_t)(srow + s * 32) * 128 + scb,
                (char*)kld[0] + w * 1024 + s * 4096);
        gload16(vb + (size_t)(srow + s * 32) * 2048 + scb,
                (char*)vld[0] + w * 1024 + s * 4096);
    }
    __syncthreads();

    f32x16 acc[2] = {};
    float mst = -1e30f, lst = 0.f;
    const int qmax = qt * 128 + w * 32 + 31;
    char* pw = (char*)pld[w];

    const int ntiles = 2 * qt + 2;
    for (int kvt = 0; kvt < ntiles; kvt++) {
        const int cur = kvt & 1;
        if (kvt + 1 < ntiles) {  // prefetch next K/V tile
#pragma unroll
            for (int s = 0; s < 2; s++) {
                gload16(kb + (size_t)((kvt + 1) * 64 + srow + s * 32) * 128 + scb,
                        (char*)kld[cur ^ 1] + w * 1024 + s * 4096);
                gload16(vb + (size_t)(srow + s * 32) * 2048 + (kvt + 1) * 128 + scb,
                        (char*)vld[cur ^ 1] + w * 1024 + s * 4096);
            }
        }
        if (kvt * 64 <= qmax) {  // tile has at least one visible column for this wave
            const char* kbase = (const char*)kld[cur];
            const char* vbase = (const char*)vld[cur];
            // S^T = K . Q^T   (rows kv, cols q)
            f32x16 s0 = {}, s1 = {};
            __builtin_amdgcn_s_setprio(1);
#pragma unroll
            for (int kc = 0; kc < 4; kc++) {
                const int r0 = q5, r1 = 32 + q5;
                bf16x8 kf0 = *(const bf16x8*)(kbase + r0 * 128 +
                                              ((kc * 32 + h2 * 16) ^ ((r0 & 7) << 4)));
                bf16x8 kf1 = *(const bf16x8*)(kbase + r1 * 128 +
                                              ((kc * 32 + h2 * 16) ^ ((r1 & 7) << 4)));
                s0 = __builtin_amdgcn_mfma_f32_32x32x16_bf16(kf0, qf[kc], s0, 0, 0, 0);
                s1 = __builtin_amdgcn_mfma_f32_32x32x16_bf16(kf1, qf[kc], s1, 0, 0, 0);
            }
            __builtin_amdgcn_s_setprio(0);
            // causal mask (S^T reg r -> kv = (r&3)+8*(r>>2)+4*h2)
            if (kvt * 64 + 63 > qt * 128 + w * 32) {
                const int qg_ = qrow_g, kvb0 = kvt * 64 + 4 * h2;
#pragma unroll
                for (int r = 0; r < 16; r++) {
                    const int kvo = (r & 3) + 8 * (r >> 2);
                    if (kvb0 + kvo > qg_) s0[r] = -1e30f;
                    if (kvb0 + 32 + kvo > qg_) s1[r] = -1e30f;
                }
            }
            // lane-local online softmax (lane owns q-row q5; h2 halves duplicate)
            float pmax = fmaxf(redmax16(s0), redmax16(s1));
            pmax = fmaxf(pmax, __shfl_xor(pmax, 32));
            const float mn = fmaxf(mst, pmax);
            const float corr = __expf(mst - mn);
            mst = mn;
#pragma unroll
            for (int r = 0; r < 16; r++) {
                s0[r] = __expf(s0[r] - mn);
                s1[r] = __expf(s1[r] - mn);
            }
            float rs = redsum16(s0) + redsum16(s1);
            rs += __shfl_xor(rs, 32);
            lst = lst * corr + rs;
#pragma unroll
            for (int r = 0; r < 16; r++) { acc[0][r] *= corr; acc[1][r] *= corr; }
            // P -> per-wave LDS [q][kv] (pairs; swizzled), intra-wave dep only
            const int swz = (q5 & 7) << 4;
#pragma unroll
            for (int a = 0; a < 8; a++) {
                const int kv0 = ((2 * a) & 3) + 8 * (a >> 1) + 4 * h2;
                u32 pk0 = (u32)bfbits(s0[2 * a]) | ((u32)bfbits(s0[2 * a + 1]) << 16);
                u32 pk1 = (u32)bfbits(s1[2 * a]) | ((u32)bfbits(s1[2 * a + 1]) << 16);
                *(u32*)(pw + q5 * 128 + ((kv0 * 2) ^ swz)) = pk0;
                *(u32*)(pw + q5 * 128 + (((kv0 + 32) * 2) ^ swz)) = pk1;
            }
            // O^T += V^T . P^T
            bf16x8 pf[4];
#pragma unroll
            for (int m = 0; m < 4; m++)
                pf[m] = *(const bf16x8*)(pw + q5 * 128 + ((m * 32 + h2 * 16) ^ swz));
            __builtin_amdgcn_s_setprio(1);
#pragma unroll
            for (int m = 0; m < 4; m++) {
#pragma unroll
                for (int db = 0; db < 2; db++) {
                    const int rd = db * 32 + q5;
                    bf16x8 vf = *(const bf16x8*)(vbase + rd * 128 +
                                                 ((m * 32 + h2 * 16) ^ ((rd & 7) << 4)));
                    acc[db] = __builtin_amdgcn_mfma_f32_32x32x16_bf16(vf, pf[m], acc[db], 0, 0, 0);
                }
            }
            __builtin_amdgcn_s_setprio(0);
        }
        __syncthreads();  // prefetched tile ready; all waves done with buf[cur]
    }

    // epilogue: acc[db][r] = O[q = qrow_g][d = db*32 + (r&3) + 8*(r>>2) + 4*h2]
    const int b = bh / H_, h = bh % H_;
    const float inv = 1.0f / lst;
    u16* orow = ao + (size_t)(b * T_ + qrow_g) * C_ + h * 64 + 4 * h2;
#pragma unroll
    for (int db = 0; db < 2; db++)
#pragma unroll
        for (int q2 = 0; q2 < 4; q2++) {
            u16x4 pk;
#pragma unroll
            for (int e = 0; e < 4; e++) pk[e] = bfbits(acc[db][q2 * 4 + e] * inv);
            *(u16x4*)(orow + db * 32 + q2 * 8) = pk;
        }
}

// ---------------- launch ----------------

extern "C" void kernel_launch(void* const* d_in, const int* in_sizes, int n_in,
                              void* d_out, int out_size, void* d_ws, size_t ws_size,
                              hipStream_t stream) {
    const float* x     = (const float*)d_in[0];
    // d_in[1] = mask (causal tril) -- structure hard-coded
    const float* Wqkv  = (const float*)d_in[2];
    const float* bqkv  = (const float*)d_in[3];
    const float* Wproj = (const float*)d_in[4];
    const float* bproj = (const float*)d_in[5];
    float* out = (float*)d_out;

    char* ws = (char*)d_ws;
    u16* xb     = (u16*)(ws);                 // 12,582,912 B
    u16* wqkvT  = (u16*)(ws + 12582912);      //  3,538,944 B
    u16* wprojT = (u16*)(ws + 16121856);      //  1,179,648 B
    u16* qw     = (u16*)(ws + 17301504);      // 12,582,912 B  [B,H,T,64] (pre-scaled)
    u16* kw     = (u16*)(ws + 29884416);      // 12,582,912 B  [B,H,T,64]
    u16* vw     = (u16*)(ws + 42467328);      // 12,582,912 B  [B,H,64,T] (transposed)
    u16* ao     = (u16*)(ws + 55050240);      // 12,582,912 B  [B*T, C]

    cvt_x_kern<<<(M1 * C_ / 8 + 255) / 256, 256, 0, stream>>>(x, xb, M1 * C_ / 8);
    cvt_w_kern<<<dim3(N1 / 32 + C_ / 32, KD / 32), 256, 0, stream>>>(
        Wqkv, Wproj, wqkvT, wprojT);

    gemm_bt_kern<0><<<(M1 / 128) * (N1 / 128), 256, 0, stream>>>(
        xb, wqkvT, bqkv, N1 / 128, qw, kw, vw, nullptr);

    attn_fwd_kern<<<B_ * H_ * (T_ / 128), 256, 0, stream>>>(qw, kw, vw, ao);

    gemm_bt_kern<1><<<(M1 / 128) * (C_ / 128), 256, 0, stream>>>(
        ao, wprojT, bproj, C_ / 128, nullptr, nullptr, nullptr, out);
}